// Round 14
// baseline (75.791 us; speedup 1.0000x reference)
//
#include <hip/hip_runtime.h>

constexpr int NP = 12288;   // N points
constexpr int NB = 4;       // batches
constexpr int MC = 1024;    // M context
constexpr int DM = 256;     // D
constexpr int KVD = 512;    // KV feature dim
constexpr int NH = 8;       // heads
constexpr int DH = 32;      // head dim

typedef __bf16 bf16x8 __attribute__((ext_vector_type(8)));
typedef __bf16 bf16x4 __attribute__((ext_vector_type(4)));
typedef float f32x4v __attribute__((ext_vector_type(4)));

__device__ inline bf16x8 pack8(float4 a, float4 b) {
    bf16x8 r;
    r[0] = (__bf16)a.x; r[1] = (__bf16)a.y; r[2] = (__bf16)a.z; r[3] = (__bf16)a.w;
    r[4] = (__bf16)b.x; r[5] = (__bf16)b.y; r[6] = (__bf16)b.z; r[7] = (__bf16)b.w;
    return r;
}

// Q + K + V projections, LN1 fused, weights converted on the fly.
// blocks [0,384):   Q path, 128x64 tiles: LN(F) on the fly (stats pre-pass),
//                   bf16 out scaled by qscale; col0==0 blocks also write
//                   q_in_b (the LN output, needed as residual by gemmo).
// blocks [384,896): K/V path (64x64 tiles, K=512), fragment-layout out.
// blocks [896,928): Wo fp32->bf16 conversion.
// block  928:       starts via binary search.
__global__ __launch_bounds__(256) void k_qkv(const float* __restrict__ F,
        const float* __restrict__ Wqf, const float* __restrict__ bq,
        const float* __restrict__ Yf,
        const float* __restrict__ Wkf, const float* __restrict__ bk,
        const float* __restrict__ Wvf, const float* __restrict__ bv,
        const float* __restrict__ Wof,
        const float* __restrict__ lng, const float* __restrict__ lnb,
        const int* __restrict__ bidx,
        __bf16* __restrict__ q_in_b, __bf16* __restrict__ Qo,
        __bf16* __restrict__ Kf, __bf16* __restrict__ Vf,
        __bf16* __restrict__ Wo_b, int* __restrict__ starts, float qscale) {
    __shared__ __bf16 As[128][68];
    __shared__ __bf16 Bs[64][68];
    __shared__ float mu_s[128], rr_s[128];
    const int t = threadIdx.x;
    const int w = t >> 6, l = t & 63, lg = l >> 4, ln = l & 15;
    const int wr = w >> 1, wc = w & 1;
    const int ar = t >> 3, ac8 = (t & 7) * 8;
    const int bid = blockIdx.x;
    if (bid < 384) {
        // ---------------- Q path with fused LN ----------------
        const int row0 = (bid >> 2) * 128, col0 = (bid & 3) * 64;
        {   // LN stats: 8 threads per row, 32 cols each
            const int c0 = (t & 7) * 32;
            for (int rg = 0; rg < 4; ++rg) {
                int row = row0 + ar + rg * 32;
                float s = 0.f, ss = 0.f;
#pragma unroll
                for (int j = 0; j < 8; ++j) {
                    float4 v = *(const float4*)&F[(size_t)row * DM + c0 + 4 * j];
                    s += (v.x + v.y) + (v.z + v.w);
                    ss += (v.x * v.x + v.y * v.y) + (v.z * v.z + v.w * v.w);
                }
                s += __shfl_xor(s, 1); ss += __shfl_xor(ss, 1);
                s += __shfl_xor(s, 2); ss += __shfl_xor(ss, 2);
                s += __shfl_xor(s, 4); ss += __shfl_xor(ss, 4);
                if ((t & 7) == 0) {
                    float mu = s * (1.f / DM);
                    float var = ss * (1.f / DM) - mu * mu;
                    mu_s[ar + rg * 32] = mu;
                    rr_s[ar + rg * 32] = rsqrtf(var + 1e-5f);
                }
            }
        }
        f32x4v acc[4][2] = {};
        for (int k0 = 0; k0 < DM; k0 += 64) {
            __syncthreads();   // stats ready (iter 0) / prior MFMA reads done
            float4 g0 = *(const float4*)&lng[k0 + ac8];
            float4 g1 = *(const float4*)&lng[k0 + ac8 + 4];
            float4 e0 = *(const float4*)&lnb[k0 + ac8];
            float4 e1 = *(const float4*)&lnb[k0 + ac8 + 4];
#pragma unroll
            for (int rg = 0; rg < 4; ++rg) {
                int rl = ar + rg * 32;
                float mu = mu_s[rl], rr = rr_s[rl];
                size_t base = (size_t)(row0 + rl) * DM + k0 + ac8;
                float4 v0 = *(const float4*)&F[base];
                float4 v1 = *(const float4*)&F[base + 4];
                bf16x8 o;
                o[0] = (__bf16)((v0.x - mu) * rr * g0.x + e0.x);
                o[1] = (__bf16)((v0.y - mu) * rr * g0.y + e0.y);
                o[2] = (__bf16)((v0.z - mu) * rr * g0.z + e0.z);
                o[3] = (__bf16)((v0.w - mu) * rr * g0.w + e0.w);
                o[4] = (__bf16)((v1.x - mu) * rr * g1.x + e1.x);
                o[5] = (__bf16)((v1.y - mu) * rr * g1.y + e1.y);
                o[6] = (__bf16)((v1.z - mu) * rr * g1.z + e1.z);
                o[7] = (__bf16)((v1.w - mu) * rr * g1.w + e1.w);
                *(bf16x8*)&As[rl][ac8] = o;
                if (col0 == 0) *(bf16x8*)&q_in_b[base] = o;
            }
            {
                size_t wb = (size_t)(col0 + ar) * DM + k0 + ac8;
                float4 w0 = *(const float4*)&Wqf[wb];
                float4 w1 = *(const float4*)&Wqf[wb + 4];
                *(bf16x8*)&Bs[ar][ac8] = pack8(w0, w1);
                wb = (size_t)(col0 + ar + 32) * DM + k0 + ac8;
                w0 = *(const float4*)&Wqf[wb];
                w1 = *(const float4*)&Wqf[wb + 4];
                *(bf16x8*)&Bs[ar + 32][ac8] = pack8(w0, w1);
            }
            __syncthreads();
#pragma unroll
            for (int kk = 0; kk < 2; ++kk) {
                bf16x8 bfr[2];
#pragma unroll
                for (int ni = 0; ni < 2; ++ni) {
                    bf16x4 lo = *(const bf16x4*)&Bs[wc * 32 + ni * 16 + ln][kk * 32 + lg * 4];
                    bf16x4 hi = *(const bf16x4*)&Bs[wc * 32 + ni * 16 + ln][kk * 32 + 16 + lg * 4];
                    bfr[ni] = __builtin_shufflevector(lo, hi, 0, 1, 2, 3, 4, 5, 6, 7);
                }
#pragma unroll
                for (int mi = 0; mi < 4; ++mi) {
                    bf16x4 lo = *(const bf16x4*)&As[wr * 64 + mi * 16 + ln][kk * 32 + lg * 4];
                    bf16x4 hi = *(const bf16x4*)&As[wr * 64 + mi * 16 + ln][kk * 32 + 16 + lg * 4];
                    bf16x8 af = __builtin_shufflevector(lo, hi, 0, 1, 2, 3, 4, 5, 6, 7);
#pragma unroll
                    for (int ni = 0; ni < 2; ++ni)
                        acc[mi][ni] = __builtin_amdgcn_mfma_f32_16x16x32_bf16(bfr[ni], af, acc[mi][ni], 0, 0, 0);
                }
            }
        }
#pragma unroll
        for (int mi = 0; mi < 4; ++mi)
#pragma unroll
            for (int ni = 0; ni < 2; ++ni) {
                int cb = col0 + wc * 32 + ni * 16 + 4 * lg;
                float4 b4 = *(const float4*)&bq[cb];
                size_t row = row0 + wr * 64 + mi * 16 + ln;
                bf16x4 pk;
                pk[0] = (__bf16)((acc[mi][ni][0] + b4.x) * qscale);
                pk[1] = (__bf16)((acc[mi][ni][1] + b4.y) * qscale);
                pk[2] = (__bf16)((acc[mi][ni][2] + b4.z) * qscale);
                pk[3] = (__bf16)((acc[mi][ni][3] + b4.w) * qscale);
                *(bf16x4*)&Qo[row * DM + cb] = pk;
            }
    } else if (bid < 896) {
        // ---------------- K/V path (64-row tiles) ----------------
        f32x4v acc[2][2] = {};
        const int K = KVD;
        const int idx = bid - 384;
        const int bx = idx & 7, row0 = (idx >> 3) * 64;
        const bool vpath = bx >= 4;
        const int col0 = (bx & 3) * 64;
        const float* Wmf = vpath ? Wvf : Wkf;
        const float* bi = vpath ? bv : bk;
        float4 a0, a1, a2, a3, w0, w1, w2, w3;
#define LOADGK(K0) \
        a0 = *(const float4*)&Yf[(size_t)(row0 + ar) * K + (K0) + ac8];            \
        a1 = *(const float4*)&Yf[(size_t)(row0 + ar) * K + (K0) + ac8 + 4];        \
        a2 = *(const float4*)&Yf[(size_t)(row0 + ar + 32) * K + (K0) + ac8];       \
        a3 = *(const float4*)&Yf[(size_t)(row0 + ar + 32) * K + (K0) + ac8 + 4];   \
        w0 = *(const float4*)&Wmf[(size_t)(col0 + ar) * K + (K0) + ac8];           \
        w1 = *(const float4*)&Wmf[(size_t)(col0 + ar) * K + (K0) + ac8 + 4];       \
        w2 = *(const float4*)&Wmf[(size_t)(col0 + ar + 32) * K + (K0) + ac8];      \
        w3 = *(const float4*)&Wmf[(size_t)(col0 + ar + 32) * K + (K0) + ac8 + 4];
        LOADGK(0)
        for (int k0 = 0; k0 < K; k0 += 64) {
            __syncthreads();
            *(bf16x8*)&As[ar][ac8] = pack8(a0, a1);
            *(bf16x8*)&As[ar + 32][ac8] = pack8(a2, a3);
            *(bf16x8*)&Bs[ar][ac8] = pack8(w0, w1);
            *(bf16x8*)&Bs[ar + 32][ac8] = pack8(w2, w3);
            __syncthreads();
            if (k0 + 64 < K) { LOADGK(k0 + 64) }
#pragma unroll
            for (int kk = 0; kk < 2; ++kk) {
                bf16x8 bfr[2];
#pragma unroll
                for (int ni = 0; ni < 2; ++ni) {
                    bf16x4 lo = *(const bf16x4*)&Bs[wc * 32 + ni * 16 + ln][kk * 32 + lg * 4];
                    bf16x4 hi = *(const bf16x4*)&Bs[wc * 32 + ni * 16 + ln][kk * 32 + 16 + lg * 4];
                    bfr[ni] = __builtin_shufflevector(lo, hi, 0, 1, 2, 3, 4, 5, 6, 7);
                }
#pragma unroll
                for (int mi = 0; mi < 2; ++mi) {
                    bf16x4 lo = *(const bf16x4*)&As[wr * 32 + mi * 16 + ln][kk * 32 + lg * 4];
                    bf16x4 hi = *(const bf16x4*)&As[wr * 32 + mi * 16 + ln][kk * 32 + 16 + lg * 4];
                    bf16x8 af = __builtin_shufflevector(lo, hi, 0, 1, 2, 3, 4, 5, 6, 7);
#pragma unroll
                    for (int ni = 0; ni < 2; ++ni) {
                        if (vpath)
                            acc[mi][ni] = __builtin_amdgcn_mfma_f32_16x16x32_bf16(af, bfr[ni], acc[mi][ni], 0, 0, 0);
                        else
                            acc[mi][ni] = __builtin_amdgcn_mfma_f32_16x16x32_bf16(bfr[ni], af, acc[mi][ni], 0, 0, 0);
                    }
                }
            }
        }
#undef LOADGK
        if (vpath) {
            const int h = (col0 + wc * 32) >> 5;
#pragma unroll
            for (int mi = 0; mi < 2; ++mi)
#pragma unroll
                for (int ni = 0; ni < 2; ++ni) {
                    int C = col0 + wc * 32 + ni * 16 + ln;
                    int nt = (C >> 4) & 1;
                    float bvv = bi[C];
                    int m = row0 + wr * 32 + mi * 16 + 4 * lg;
                    int b = m >> 10, mlocal = m & 1023;
                    int mhg = mlocal >> 5;
                    bf16x4 pk;
#pragma unroll
                    for (int r = 0; r < 4; ++r) pk[r] = (__bf16)(acc[mi][ni][r] + bvv);
                    *(bf16x4*)&Vf[(size_t)(((b * NH + h) * 32 + mhg) * 2 + nt) * 512 + l * 8 + mi * 4] = pk;
                }
        } else {
            const int h = (col0 + wc * 32) >> 5;
#pragma unroll
            for (int mi = 0; mi < 2; ++mi) {
                int m = row0 + wr * 32 + mi * 16 + ln;
                int b = m >> 10, mlocal = m & 1023;
                int msg = mlocal >> 4;
#pragma unroll
                for (int ni = 0; ni < 2; ++ni) {
                    int cb = col0 + wc * 32 + ni * 16 + 4 * lg;
                    float4 b4 = *(const float4*)&bi[cb];
                    bf16x4 pk;
                    pk[0] = (__bf16)(acc[mi][ni][0] + b4.x);
                    pk[1] = (__bf16)(acc[mi][ni][1] + b4.y);
                    pk[2] = (__bf16)(acc[mi][ni][2] + b4.z);
                    pk[3] = (__bf16)(acc[mi][ni][3] + b4.w);
                    *(bf16x4*)&Kf[(size_t)((b * NH + h) * 64 + msg) * 512 + l * 8 + ni * 4] = pk;
                }
            }
        }
    } else if (bid < 928) {
        // ---------------- Wo fp32 -> bf16 ----------------
        size_t i = ((size_t)(bid - 896) * 256 + t) * 8;
        float4 v0 = *(const float4*)&Wof[i];
        float4 v1 = *(const float4*)&Wof[i + 4];
        *(bf16x8*)&Wo_b[i] = pack8(v0, v1);
    } else {
        // ---------------- starts ----------------
        if (t <= NB) {
            int lo = 0, hi = NP;
            while (lo < hi) { int mid = (lo + hi) >> 1; if (bidx[mid] < t) lo = mid + 1; else hi = mid; }
            starts[t] = lo;
        }
    }
}

// Flash cross-attention (round-11 structure): ZERO LDS, ZERO barriers,
// fragment-layout K/V in global (L2-resident), NO-MAX exp2 softmax,
// 128 q-rows per block (2 Q frags/wave sharing every K/V fragment).
__global__ __launch_bounds__(256) void k_attn_mfma(const __bf16* __restrict__ q,
        const __bf16* __restrict__ Kf, const __bf16* __restrict__ Vf,
        const int* __restrict__ starts, __bf16* __restrict__ o) {
    const int b = blockIdx.z, h = blockIdx.y;
    const int r0 = starts[b] + blockIdx.x * 128;
    const int rend = starts[b + 1];
    if (r0 >= rend) return;
    const int nr = min(128, rend - r0);

    const int t = threadIdx.x;
    const int w = t >> 6, l = t & 63, lg = l >> 4, ln = l & 15;

    const __bf16* kfb = Kf + (size_t)(b * NH + h) * 32768;
    const __bf16* vfb = Vf + (size_t)(b * NH + h) * 32768;

    const int qr0 = min(r0 + w * 32 + ln, NP - 1);
    const int qr1 = min(r0 + w * 32 + 16 + ln, NP - 1);
    const __bf16* qp0 = q + (size_t)qr0 * DM + h * DH;
    const __bf16* qp1 = q + (size_t)qr1 * DM + h * DH;
    bf16x8 qf0 = __builtin_shufflevector(*(const bf16x4*)(qp0 + lg * 4),
                                         *(const bf16x4*)(qp0 + 16 + lg * 4),
                                         0, 1, 2, 3, 4, 5, 6, 7);
    bf16x8 qf1 = __builtin_shufflevector(*(const bf16x4*)(qp1 + lg * 4),
                                         *(const bf16x4*)(qp1 + 16 + lg * 4),
                                         0, 1, 2, 3, 4, 5, 6, 7);

    f32x4v OaccA[2] = {{0.f, 0.f, 0.f, 0.f}, {0.f, 0.f, 0.f, 0.f}};
    f32x4v OaccB[2] = {{0.f, 0.f, 0.f, 0.f}, {0.f, 0.f, 0.f, 0.f}};
    float lsA4[4] = {0.f, 0.f, 0.f, 0.f};
    float lsB4[4] = {0.f, 0.f, 0.f, 0.f};

    for (int mt = 0; mt < 8; ++mt) {
        bf16x8 kfr[8];
#pragma unroll
        for (int ms = 0; ms < 8; ++ms)
            kfr[ms] = *(const bf16x8*)&kfb[(size_t)((mt * 8 + ms) * 64 + l) * 8];
        f32x4v S0[8], S1[8];
        __builtin_amdgcn_s_setprio(1);
#pragma unroll
        for (int ms = 0; ms < 8; ++ms) {
            S0[ms] = __builtin_amdgcn_mfma_f32_16x16x32_bf16(
                kfr[ms], qf0, (f32x4v){0.f, 0.f, 0.f, 0.f}, 0, 0, 0);
            S1[ms] = __builtin_amdgcn_mfma_f32_16x16x32_bf16(
                kfr[ms], qf1, (f32x4v){0.f, 0.f, 0.f, 0.f}, 0, 0, 0);
        }
        __builtin_amdgcn_s_setprio(0);
        bf16x8 vfr[8];
#pragma unroll
        for (int i = 0; i < 8; ++i)
            vfr[i] = *(const bf16x8*)&vfb[(size_t)((mt * 8 + i) * 64 + l) * 8];
        bf16x8 pa0[4], pa1[4];
#pragma unroll
        for (int ms = 0; ms < 8; ++ms) {
            const int mh = ms >> 1, j0 = (ms & 1) * 4;
#pragma unroll
            for (int r = 0; r < 4; ++r) {
                float e = __builtin_amdgcn_exp2f(S0[ms][r]);
                lsA4[r] += e;
                pa0[mh][j0 + r] = (__bf16)e;
            }
#pragma unroll
            for (int r = 0; r < 4; ++r) {
                float e = __builtin_amdgcn_exp2f(S1[ms][r]);
                lsB4[r] += e;
                pa1[mh][j0 + r] = (__bf16)e;
            }
        }
        __builtin_amdgcn_s_setprio(1);
#pragma unroll
        for (int mh = 0; mh < 4; ++mh)
#pragma unroll
            for (int nt = 0; nt < 2; ++nt) {
                OaccA[nt] = __builtin_amdgcn_mfma_f32_16x16x32_bf16(pa0[mh], vfr[mh * 2 + nt], OaccA[nt], 0, 0, 0);
                OaccB[nt] = __builtin_amdgcn_mfma_f32_16x16x32_bf16(pa1[mh], vfr[mh * 2 + nt], OaccB[nt], 0, 0, 0);
            }
        __builtin_amdgcn_s_setprio(0);
    }
    float lsA = (lsA4[0] + lsA4[1]) + (lsA4[2] + lsA4[3]);
    float lsB = (lsB4[0] + lsB4[1]) + (lsB4[2] + lsB4[3]);
    lsA += __shfl_xor(lsA, 16); lsA += __shfl_xor(lsA, 32);
    lsB += __shfl_xor(lsB, 16); lsB += __shfl_xor(lsB, 32);
    float invA = 1.0f / lsA, invB = 1.0f / lsB;
    float ivA[4], ivB[4];
#pragma unroll
    for (int r = 0; r < 4; ++r) {
        ivA[r] = __shfl(invA, 4 * lg + r);
        ivB[r] = __shfl(invB, 4 * lg + r);
    }
#pragma unroll
    for (int r = 0; r < 4; ++r) {
        int rlocA = w * 32 + 4 * lg + r;
        if (rlocA < nr) {
            size_t base = (size_t)(r0 + rlocA) * DM + h * DH + ln;
            o[base] = (__bf16)(OaccA[0][r] * ivA[r]);
            o[base + 16] = (__bf16)(OaccA[1][r] * ivA[r]);
        }
        int rlocB = w * 32 + 16 + 4 * lg + r;
        if (rlocB < nr) {
            size_t base = (size_t)(r0 + rlocB) * DM + h * DH + ln;
            o[base] = (__bf16)(OaccB[0][r] * ivB[r]);
            o[base + 16] = (__bf16)(OaccB[1][r] * ivB[r]);
        }
    }
}

// Wo projection + residual + final LayerNorm, fused. Tile 32 rows x 256 cols.
__global__ __launch_bounds__(256) void k_gemmo_ln(const __bf16* __restrict__ A,
        const __bf16* __restrict__ W, const float* __restrict__ bias,
        const __bf16* __restrict__ resid, const float* __restrict__ g,
        const float* __restrict__ bb, float* __restrict__ out) {
    __shared__ __bf16 As[32][68];
    __shared__ __bf16 Bs[256][68];
    __shared__ float red[32][4][2];
    const int t = threadIdx.x;
    const int w = t >> 6, l = t & 63, lg = l >> 4, ln = l & 15;
    const int row0 = blockIdx.x * 32;
    const int ar = t >> 3, ac8 = (t & 7) * 8;
    f32x4v acc[2][4] = {};
    for (int k0 = 0; k0 < DM; k0 += 64) {
        __syncthreads();
        *(bf16x8*)&As[ar][ac8] = *(const bf16x8*)&A[(size_t)(row0 + ar) * DM + k0 + ac8];
#pragma unroll
        for (int j = 0; j < 8; ++j)
            *(bf16x8*)&Bs[ar + 32 * j][ac8] = *(const bf16x8*)&W[(size_t)(ar + 32 * j) * DM + k0 + ac8];
        __syncthreads();
#pragma unroll
        for (int kk = 0; kk < 2; ++kk) {
            bf16x8 bfr[4];
#pragma unroll
            for (int ni = 0; ni < 4; ++ni) {
                bf16x4 lo = *(const bf16x4*)&Bs[w * 64 + ni * 16 + ln][kk * 32 + lg * 4];
                bf16x4 hi = *(const bf16x4*)&Bs[w * 64 + ni * 16 + ln][kk * 32 + 16 + lg * 4];
                bfr[ni] = __builtin_shufflevector(lo, hi, 0, 1, 2, 3, 4, 5, 6, 7);
            }
#pragma unroll
            for (int mi = 0; mi < 2; ++mi) {
                bf16x4 lo = *(const bf16x4*)&As[mi * 16 + ln][kk * 32 + lg * 4];
                bf16x4 hi = *(const bf16x4*)&As[mi * 16 + ln][kk * 32 + 16 + lg * 4];
                bf16x8 af = __builtin_shufflevector(lo, hi, 0, 1, 2, 3, 4, 5, 6, 7);
#pragma unroll
                for (int ni = 0; ni < 4; ++ni)
                    acc[mi][ni] = __builtin_amdgcn_mfma_f32_16x16x32_bf16(bfr[ni], af, acc[mi][ni], 0, 0, 0);
            }
        }
    }
    float s[2] = {0.f, 0.f}, ss[2] = {0.f, 0.f};
#pragma unroll
    for (int mi = 0; mi < 2; ++mi) {
        int row = row0 + mi * 16 + ln;
#pragma unroll
        for (int ni = 0; ni < 4; ++ni) {
            int cb = w * 64 + ni * 16 + lg * 4;
            float4 b4 = *(const float4*)&bias[cb];
            bf16x4 rv = *(const bf16x4*)&resid[(size_t)row * DM + cb];
            float z0 = acc[mi][ni][0] + b4.x + (float)rv[0];
            float z1 = acc[mi][ni][1] + b4.y + (float)rv[1];
            float z2 = acc[mi][ni][2] + b4.z + (float)rv[2];
            float z3 = acc[mi][ni][3] + b4.w + (float)rv[3];
            acc[mi][ni][0] = z0; acc[mi][ni][1] = z1;
            acc[mi][ni][2] = z2; acc[mi][ni][3] = z3;
            s[mi] += (z0 + z1) + (z2 + z3);
            ss[mi] += (z0 * z0 + z1 * z1) + (z2 * z2 + z3 * z3);
        }
    }
#pragma unroll
    for (int mi = 0; mi < 2; ++mi) {
        s[mi] += __shfl_xor(s[mi], 16);  s[mi] += __shfl_xor(s[mi], 32);
        ss[mi] += __shfl_xor(ss[mi], 16); ss[mi] += __shfl_xor(ss[mi], 32);
    }
    if (l < 16) {
#pragma unroll
        for (int mi = 0; mi < 2; ++mi) {
            red[mi * 16 + ln][w][0] = s[mi];
            red[mi * 16 + ln][w][1] = ss[mi];
        }
    }
    __syncthreads();
#pragma unroll
    for (int mi = 0; mi < 2; ++mi) {
        int rloc = mi * 16 + ln;
        float su = (red[rloc][0][0] + red[rloc][1][0]) + (red[rloc][2][0] + red[rloc][3][0]);
        float sq = (red[rloc][0][1] + red[rloc][1][1]) + (red[rloc][2][1] + red[rloc][3][1]);
        float mu = su * (1.f / DM);
        float var = sq * (1.f / DM) - mu * mu;
        float rs = rsqrtf(var + 1e-5f);
        size_t row = row0 + rloc;
#pragma unroll
        for (int ni = 0; ni < 4; ++ni) {
            int cb = w * 64 + ni * 16 + lg * 4;
            float4 g4 = *(const float4*)&g[cb];
            float4 bb4 = *(const float4*)&bb[cb];
            float4 o4;
            o4.x = (acc[mi][ni][0] - mu) * rs * g4.x + bb4.x;
            o4.y = (acc[mi][ni][1] - mu) * rs * g4.y + bb4.y;
            o4.z = (acc[mi][ni][2] - mu) * rs * g4.z + bb4.z;
            o4.w = (acc[mi][ni][3] - mu) * rs * g4.w + bb4.w;
            *(float4*)&out[row * DM + cb] = o4;
        }
    }
}

extern "C" void kernel_launch(void* const* d_in, const int* in_sizes, int n_in,
                              void* d_out, int out_size, void* d_ws, size_t ws_size,
                              hipStream_t stream) {
    const float* F  = (const float*)d_in[0];
    const int* bidx = (const int*)d_in[1];
    const float* y  = (const float*)d_in[2];
    const float* Wq = (const float*)d_in[3];
    const float* bq = (const float*)d_in[4];
    const float* Wk = (const float*)d_in[5];
    const float* bk = (const float*)d_in[6];
    const float* Wv = (const float*)d_in[7];
    const float* bv = (const float*)d_in[8];
    const float* Wo = (const float*)d_in[9];
    const float* bo = (const float*)d_in[10];
    const float* lg = (const float*)d_in[11];
    const float* lb = (const float*)d_in[12];
    float* out = (float*)d_out;

    char* ws = (char*)d_ws;
    __bf16* q_in_b = (__bf16*)ws;   ws += (size_t)NP * DM * 2;
    __bf16* qb     = (__bf16*)ws;   ws += (size_t)NP * DM * 2;
    __bf16* ob     = (__bf16*)ws;   ws += (size_t)NP * DM * 2;
    __bf16* Kf     = (__bf16*)ws;   ws += (size_t)NB * MC * DM * 2;
    __bf16* Vf     = (__bf16*)ws;   ws += (size_t)NB * DM * MC * 2;
    __bf16* Wo_b   = (__bf16*)ws;   ws += (size_t)DM * DM * 2;
    int* starts    = (int*)ws;

    const float qscale = 0.17677669529663687f * 1.4426950408889634f; // 1/sqrt(32)*log2e

    k_qkv<<<929, 256, 0, stream>>>(F, Wq, bq, y, Wk, bk, Wv, bv, Wo, lg, lb, bidx,
            q_in_b, qb, Kf, Vf, Wo_b, starts, qscale);
    k_attn_mfma<<<dim3(NP / 128, NH, NB), 256, 0, stream>>>(qb, Kf, Vf, starts, ob);
    k_gemmo_ln<<<NP / 32, 256, 0, stream>>>(ob, Wo_b, bo, q_in_b, lg, lb, out);
}